// Round 12
// baseline (1188.808 us; speedup 1.0000x reference)
//
#include <hip/hip_runtime.h>

#define BETA 0.95f

// ---------------- LIF helper: snntorch Leaky, reset_mechanism='subtract' ----
__device__ __forceinline__ void lif_store(float inp, float* __restrict__ mem,
                                          float* __restrict__ spk, size_t idx, int t) {
    float m = t ? mem[idx] : 0.0f;
    float r = (m > 1.0f) ? 1.0f : 0.0f;
    m = BETA * m + inp - r;
    mem[idx] = m;
    spk[idx] = (m > 1.0f) ? 1.0f : 0.0f;
}

// ---------------- weight transpose: w2[64][512] -> w2t[512][64]; w3[64][576] -> w3t[576][64]
__global__ void transpose_w23(const float* __restrict__ w2, const float* __restrict__ w3,
                              float* __restrict__ w2t, float* __restrict__ w3t) {
    int i = blockIdx.x * 256 + threadIdx.x;
    if (i < 32768) { int oc = i >> 9;  int k = i & 511;      w2t[k * 64 + oc] = w2[i]; }
    if (i < 36864) { int oc = i / 576; int k = i - oc * 576; w3t[k * 64 + oc] = w3[i]; }
}

// ---------------- conv1 + LIF: x[b,t,84,84]/255 * w1[32,1,8,8] stride4 -> [b,32,20,20]
__global__ __launch_bounds__(320) void conv1_lif(const float* __restrict__ x,
        const float* __restrict__ w1, const float* __restrict__ b1,
        float* __restrict__ mem1, float* __restrict__ s1, int t)
{
    __shared__ float xs[7056];
    __shared__ __align__(16) float wt[2048];   // [k=64][oc=32]
    __shared__ float bs[32];
    const int b = blockIdx.x, tid = threadIdx.x;
    const float* xp = x + (size_t)(b * 4 + t) * 7056;
    for (int i = tid; i < 7056; i += 320) xs[i] = xp[i] * (1.0f / 255.0f);
    for (int i = tid; i < 2048; i += 320) { int oc = i >> 6, k = i & 63; wt[k * 32 + oc] = w1[i]; }
    if (tid < 32) bs[tid] = b1[tid];
    __syncthreads();

    const int ocg = tid & 7, row = tid >> 3;    // ocg 0..7, row 0..39
    const int oc0 = ocg * 4;
    const int oy = row >> 1, ox0 = (row & 1) * 10;

    float acc[4][10];
    #pragma unroll
    for (int j = 0; j < 4; j++) {
        const float bv = bs[oc0 + j];
        #pragma unroll
        for (int i = 0; i < 10; i++) acc[j][i] = bv;
    }

    for (int ky = 0; ky < 8; ky++) {
        const float* xr = &xs[(oy * 4 + ky) * 84 + ox0 * 4];
        #pragma unroll
        for (int kx = 0; kx < 8; kx++) {
            const float4 w4 = *(const float4*)&wt[(ky * 8 + kx) * 32 + oc0];
            const float wv[4] = {w4.x, w4.y, w4.z, w4.w};
            float xv[10];
            #pragma unroll
            for (int i = 0; i < 10; i++) xv[i] = xr[kx + 4 * i];
            #pragma unroll
            for (int j = 0; j < 4; j++)
                #pragma unroll
                for (int i = 0; i < 10; i++)
                    acc[j][i] += wv[j] * xv[i];
        }
    }

    const size_t base = (size_t)b * 12800 + (size_t)oc0 * 400 + oy * 20 + ox0;
    #pragma unroll
    for (int j = 0; j < 4; j++)
        #pragma unroll
        for (int i = 0; i < 10; i++)
            lif_store(acc[j][i], mem1, s1, base + (size_t)j * 400 + i, t);
}

// ---------------- conv2 + LIF: s1[b,32,20,20] * w2[64,32,4,4] stride2 -> [b,64,9,9]
// v2: thread = 4 oc x 9 px (full output row); input row held in registers and
// reused across kx and px -> LDS cyc/FMA 2.45 -> 0.75. float4 staging.
// Accumulation order per output (icl->ky->kx) identical to v1 -> bit-identical.
// block 192 = 16 ocg x 12 rows (rows 0..8 active), grid 512 (batch).
__global__ __launch_bounds__(192) void conv2_lif(const float* __restrict__ s1,
        const float* __restrict__ w2t, const float* __restrict__ b2,
        float* __restrict__ mem2, float* __restrict__ s2, int t)
{
    __shared__ __align__(16) float ins[12800];   // [32 ic][20][20]
    __shared__ __align__(16) float wt[4096];     // [64 k][64 oc] chunk
    __shared__ float bs[64];
    const int b = blockIdx.x, tid = threadIdx.x;
    const float* ip = s1 + (size_t)b * 12800;
    for (int i = tid; i < 3200; i += 192)
        *(float4*)&ins[i * 4] = *(const float4*)&ip[i * 4];
    if (tid < 64) bs[tid] = b2[tid];

    const int ocg = tid & 15, row = tid >> 4;   // ocg 0..15, row 0..11 (active < 9)
    const int oc0 = ocg * 4;
    const bool act = (row < 9);

    float acc[4][9];
    #pragma unroll
    for (int j = 0; j < 4; j++) {
        const float bv = bs[oc0 + j];   // read before first barrier is unsafe -> init after
        (void)bv;
    }
    // defer bias init until after first __syncthreads (bs written by tid<64)

    bool inited = false;
    for (int kc = 0; kc < 512; kc += 64) {
        __syncthreads();                         // prev compute done (and input/bias staged, iter 0)
        for (int i = tid; i < 1024; i += 192)
            *(float4*)&wt[i * 4] = *(const float4*)&w2t[(size_t)kc * 64 + i * 4];
        __syncthreads();                         // wt (and, iter 0, ins/bs) visible
        if (!inited) {
            #pragma unroll
            for (int j = 0; j < 4; j++) {
                const float bv = bs[oc0 + j];
                #pragma unroll
                for (int i = 0; i < 9; i++) acc[j][i] = bv;
            }
            inited = true;
        }
        if (act) {
            const int ic0 = kc >> 4;
            #pragma unroll
            for (int icl = 0; icl < 4; icl++) {
                const float* inc = &ins[(ic0 + icl) * 400];
                #pragma unroll
                for (int ky = 0; ky < 4; ky++) {
                    const float* xr = &inc[(2 * row + ky) * 20];
                    float xv[20];
                    #pragma unroll
                    for (int q = 0; q < 5; q++) {
                        const float4 v = *(const float4*)&xr[q * 4];
                        xv[q * 4 + 0] = v.x; xv[q * 4 + 1] = v.y;
                        xv[q * 4 + 2] = v.z; xv[q * 4 + 3] = v.w;
                    }
                    #pragma unroll
                    for (int kx = 0; kx < 4; kx++) {
                        const float4 w4 = *(const float4*)&wt[(icl * 16 + ky * 4 + kx) * 64 + oc0];
                        #pragma unroll
                        for (int i = 0; i < 9; i++) {
                            const float xvv = xv[kx + 2 * i];
                            acc[0][i] += w4.x * xvv;
                            acc[1][i] += w4.y * xvv;
                            acc[2][i] += w4.z * xvv;
                            acc[3][i] += w4.w * xvv;
                        }
                    }
                }
            }
        }
    }

    if (act) {
        const size_t base = (size_t)b * 5184 + (size_t)oc0 * 81 + (size_t)row * 9;
        #pragma unroll
        for (int j = 0; j < 4; j++)
            #pragma unroll
            for (int i = 0; i < 9; i++)
                lif_store(acc[j][i], mem2, s2, base + (size_t)j * 81 + i, t);
    }
}

// ---------------- conv3 + LIF: s2[b,64,9,9] * w3[64,64,3,3] stride1 -> [b,64,7,7]
__global__ __launch_bounds__(256) void conv3_lif(const float* __restrict__ s2,
        const float* __restrict__ w3t, const float* __restrict__ b3,
        float* __restrict__ mem3, float* __restrict__ s3, int t)
{
    __shared__ float ins[5184];
    __shared__ __align__(8) float wt[72 * 64];  // [kl][oc], K-chunk 72 = 8 ic x 9
    __shared__ float bs[64];
    const int b = blockIdx.x, tid = threadIdx.x;
    const float* ip = s2 + (size_t)b * 5184;
    for (int i = tid; i < 5184; i += 256) ins[i] = ip[i];
    if (tid < 64) bs[tid] = b3[tid];

    const int ocg = tid & 31, oy = tid >> 5;    // oy 0..7
    const int oc0 = ocg * 2;
    const bool act = (oy < 7);
    __syncthreads();

    float acc[2][7];
    #pragma unroll
    for (int j = 0; j < 2; j++) {
        const float bv = bs[oc0 + j];
        #pragma unroll
        for (int i = 0; i < 7; i++) acc[j][i] = bv;
    }

    for (int kc = 0; kc < 576; kc += 72) {
        for (int i = tid; i < 4608; i += 256) wt[i] = w3t[kc * 64 + i];
        __syncthreads();
        if (act) {
            const int ic0 = kc / 9;
            #pragma unroll
            for (int icl = 0; icl < 8; icl++) {
                const float* inc = &ins[(ic0 + icl) * 81];
                #pragma unroll
                for (int ky = 0; ky < 3; ky++) {
                    const float* xr = &inc[(oy + ky) * 9];
                    float xv[9];
                    #pragma unroll
                    for (int i = 0; i < 9; i++) xv[i] = xr[i];
                    #pragma unroll
                    for (int kx = 0; kx < 3; kx++) {
                        const float2 w2v = *(const float2*)&wt[(icl * 9 + ky * 3 + kx) * 64 + oc0];
                        #pragma unroll
                        for (int i = 0; i < 7; i++) {
                            acc[0][i] += w2v.x * xv[kx + i];
                            acc[1][i] += w2v.y * xv[kx + i];
                        }
                    }
                }
            }
        }
        __syncthreads();
    }

    if (act) {
        const size_t base = (size_t)b * 3136 + (size_t)oc0 * 49 + oy * 7;
        #pragma unroll
        for (int j = 0; j < 2; j++)
            #pragma unroll
            for (int i = 0; i < 7; i++)
                lif_store(acc[j][i], mem3, s3, base + (size_t)j * 49 + i, t);
    }
}

// ---------------- transpose [512][3136] -> [3136][512], z=0: s3->s3t, z=1: wl->wlt
__global__ __launch_bounds__(256) void transpose_mk(const float* __restrict__ s3,
        const float* __restrict__ wl, float* __restrict__ s3t, float* __restrict__ wlt)
{
    __shared__ float T[64][65];
    const int c0 = blockIdx.x * 64;               // 49 tiles along K=3136
    const int r0 = blockIdx.y * 64;               // 8 tiles along M=512
    const float* src = blockIdx.z ? wl : s3;
    float* dst = blockIdx.z ? wlt : s3t;
    const int tid = threadIdx.x;
    #pragma unroll
    for (int i = 0; i < 4; i++) {
        const int f = tid + 256 * i;              // 0..1023
        const int r = f >> 4, cq = (f & 15) * 4;
        const float4 v = *(const float4*)&src[(size_t)(r0 + r) * 3136 + c0 + cq];
        T[r][cq + 0] = v.x; T[r][cq + 1] = v.y; T[r][cq + 2] = v.z; T[r][cq + 3] = v.w;
    }
    __syncthreads();
    #pragma unroll
    for (int i = 0; i < 4; i++) {
        const int f = tid + 256 * i;
        const int c = f >> 4, rq = (f & 15) * 4;
        float4 v;
        v.x = T[rq + 0][c]; v.y = T[rq + 1][c]; v.z = T[rq + 2][c]; v.w = T[rq + 3][c];
        *(float4*)&dst[(size_t)(c0 + c) * 512 + r0 + rq] = v;
    }
}

// ---------------- fc partial GEMM: out[m][n] = sum_k s3t[k][m]*wlt[k][n]
// 64x64 tile, 4x4/thread, SPLITK=7 (448 k each = 7 chunks of 64, sequential -> deterministic)
__global__ __launch_bounds__(256) void fc_gemm(const float* __restrict__ s3t,
        const float* __restrict__ wlt, float* __restrict__ part)
{
    __shared__ __align__(16) float As[64][68];
    __shared__ __align__(16) float Bs[64][68];
    const int bid = blockIdx.x;                   // 448 = 64 tiles x 7 splits
    const int tile = bid & 63, split = bid >> 6;
    const int m0 = (tile & 7) * 64, n0 = (tile >> 3) * 64;
    const int tid = threadIdx.x;
    const int tn = (tid & 15) * 4, tm = (tid >> 4) * 4;
    float acc[4][4] = {};

    for (int sc = 0; sc < 7; sc++) {
        const int kc = split * 448 + sc * 64;
        __syncthreads();
        #pragma unroll
        for (int i = 0; i < 4; i++) {
            const int f = tid + 256 * i;          // 0..1023
            const int k = f >> 4, mq = (f & 15) * 4;
            *(float4*)&As[k][mq] = *(const float4*)&s3t[(size_t)(kc + k) * 512 + m0 + mq];
            *(float4*)&Bs[k][mq] = *(const float4*)&wlt[(size_t)(kc + k) * 512 + n0 + mq];
        }
        __syncthreads();
        #pragma unroll 8
        for (int k = 0; k < 64; k++) {
            const float4 a = *(const float4*)&As[k][tm];
            const float4 b = *(const float4*)&Bs[k][tn];
            acc[0][0] += a.x * b.x; acc[0][1] += a.x * b.y; acc[0][2] += a.x * b.z; acc[0][3] += a.x * b.w;
            acc[1][0] += a.y * b.x; acc[1][1] += a.y * b.y; acc[1][2] += a.y * b.z; acc[1][3] += a.y * b.w;
            acc[2][0] += a.z * b.x; acc[2][1] += a.z * b.y; acc[2][2] += a.z * b.z; acc[2][3] += a.z * b.w;
            acc[3][0] += a.w * b.x; acc[3][1] += a.w * b.y; acc[3][2] += a.w * b.z; acc[3][3] += a.w * b.w;
        }
    }

    #pragma unroll
    for (int r = 0; r < 4; r++) {
        float4 v; v.x = acc[r][0]; v.y = acc[r][1]; v.z = acc[r][2]; v.w = acc[r][3];
        *(float4*)&part[(size_t)split * 262144 + (size_t)(m0 + tm + r) * 512 + n0 + tn] = v;
    }
}

// ---------------- fc reduce (fixed order) + bias + LIF + spike accumulate
__global__ __launch_bounds__(256) void fc_reduce_lif(const float* __restrict__ part,
        const float* __restrict__ bl, float* __restrict__ memf,
        float* __restrict__ accum, int t)
{
    const int gid = blockIdx.x * 256 + threadIdx.x;  // grid 1024 -> 262144 exact
    const int n = gid & 511;
    float s = part[gid];
    #pragma unroll
    for (int sp = 1; sp < 7; sp++) s += part[(size_t)sp * 262144 + gid];
    s += bl[n];
    const float mp = t ? memf[gid] : 0.0f;
    const float r = (mp > 1.0f) ? 1.0f : 0.0f;
    const float mnew = BETA * mp + s - r;
    memf[gid] = mnew;
    const float spk = (mnew > 1.0f) ? 1.0f : 0.0f;
    accum[gid] = (t ? accum[gid] : 0.0f) + spk;
}

// ---------------- head: out[512,18] = (acc/4) @ wh.T + bh
__global__ void head_k(const float* __restrict__ accum, const float* __restrict__ wh,
                       const float* __restrict__ bh, float* __restrict__ out)
{
    const int gid = blockIdx.x * 256 + threadIdx.x;
    if (gid >= 512 * 18) return;
    const int b = gid / 18, o = gid - b * 18;
    const float* av = accum + (size_t)b * 512;
    const float* wv = wh + (size_t)o * 512;
    float s = bh[o];
    for (int k = 0; k < 512; k++) s += (av[k] * 0.25f) * wv[k];
    out[gid] = s;
}

extern "C" void kernel_launch(void* const* d_in, const int* in_sizes, int n_in,
                              void* d_out, int out_size, void* d_ws, size_t ws_size,
                              hipStream_t stream)
{
    const float* x  = (const float*)d_in[0];
    const float* w1 = (const float*)d_in[1];
    const float* b1 = (const float*)d_in[2];
    const float* w2 = (const float*)d_in[3];
    const float* b2 = (const float*)d_in[4];
    const float* w3 = (const float*)d_in[5];
    const float* b3 = (const float*)d_in[6];
    const float* wl = (const float*)d_in[7];
    const float* bl = (const float*)d_in[8];
    const float* wh = (const float*)d_in[9];
    const float* bh = (const float*)d_in[10];

    float* ws   = (float*)d_ws;
    float* mem1 = ws;                    // [512][32][400]
    float* mem2 = mem1 + 6553600;        // [512][64][81]
    float* mem3 = mem2 + 2654208;        // [512][64][49]
    float* memf = mem3 + 1605632;        // [512][512]
    float* acc  = memf + 262144;         // [512][512]
    float* s1   = acc  + 262144;         // [512][32][400]
    float* s2   = s1 + 6553600;          // [512][64][81]
    float* s3   = s2 + 2654208;          // [512][64][49]
    float* w2t  = s3 + 1605632;          // [512][64]
    float* w3t  = w2t + 32768;           // [576][64]

    // fc scratch ALIASES s1: s1's spikes are dead after conv2(t) and rewritten by
    // conv1(t+1); all fc scratch is produced after conv3(t) and consumed by
    // fc_reduce(t) -> no overlap with s1's live range.
    float* s3t_buf = s1;                 // [3136][512]  (1,605,632 floats)
    float* wlt_buf = s1 + 1605632;       // [3136][512]  (1,605,632 floats)
    float* part    = s1 + 3211264;       // [7][512][512] (1,835,008 floats) -> total 5,046,272 < 6,553,600

    transpose_w23<<<144, 256, 0, stream>>>(w2, w3, w2t, w3t);

    for (int t = 0; t < 4; t++) {
        conv1_lif<<<512, 320, 0, stream>>>(x, w1, b1, mem1, s1, t);
        conv2_lif<<<512, 192, 0, stream>>>(s1, w2t, b2, mem2, s2, t);
        conv3_lif<<<512, 256, 0, stream>>>(s2, w3t, b3, mem3, s3, t);
        transpose_mk<<<dim3(49, 8, 2), 256, 0, stream>>>(s3, wl, s3t_buf, wlt_buf);
        fc_gemm<<<448, 256, 0, stream>>>(s3t_buf, wlt_buf, part);
        fc_reduce_lif<<<1024, 256, 0, stream>>>(part, bl, memf, acc, t);
    }
    head_k<<<36, 256, 0, stream>>>(acc, wh, bh, (float*)d_out);
}

// Round 13
// 987.756 us; speedup vs baseline: 1.2035x; 1.2035x over previous
//
#include <hip/hip_runtime.h>

#define BETA 0.95f

// ---------------- LIF helpers: snntorch Leaky, reset_mechanism='subtract' ----
__device__ __forceinline__ void lif_store(float inp, float* __restrict__ mem,
                                          float* __restrict__ spk, size_t idx, int t) {
    float m = t ? mem[idx] : 0.0f;
    float r = (m > 1.0f) ? 1.0f : 0.0f;
    m = BETA * m + inp - r;
    mem[idx] = m;
    spk[idx] = (m > 1.0f) ? 1.0f : 0.0f;
}

__device__ __forceinline__ void lif_store_u8(float inp, float* __restrict__ mem,
                                             unsigned char* __restrict__ spk, size_t idx, int t) {
    float m = t ? mem[idx] : 0.0f;
    float r = (m > 1.0f) ? 1.0f : 0.0f;
    m = BETA * m + inp - r;
    mem[idx] = m;
    spk[idx] = (m > 1.0f) ? (unsigned char)1 : (unsigned char)0;
}

// ---------------- weight transpose: w2[64][512] -> w2t[512][64]; w3[64][576] -> w3t[576][64]
__global__ void transpose_w23(const float* __restrict__ w2, const float* __restrict__ w3,
                              float* __restrict__ w2t, float* __restrict__ w3t) {
    int i = blockIdx.x * 256 + threadIdx.x;
    if (i < 32768) { int oc = i >> 9;  int k = i & 511;      w2t[k * 64 + oc] = w2[i]; }
    if (i < 36864) { int oc = i / 576; int k = i - oc * 576; w3t[k * 64 + oc] = w3[i]; }
}

// ---------------- conv1 + LIF: x[b,t,84,84]/255 * w1[32,1,8,8] stride4 -> [b,32,20,20]
// s1 spikes written as u8 (exact: spikes in {0,1}).
__global__ __launch_bounds__(320) void conv1_lif(const float* __restrict__ x,
        const float* __restrict__ w1, const float* __restrict__ b1,
        float* __restrict__ mem1, unsigned char* __restrict__ s1, int t)
{
    __shared__ float xs[7056];
    __shared__ __align__(16) float wt[2048];   // [k=64][oc=32]
    __shared__ float bs[32];
    const int b = blockIdx.x, tid = threadIdx.x;
    const float* xp = x + (size_t)(b * 4 + t) * 7056;
    for (int i = tid; i < 7056; i += 320) xs[i] = xp[i] * (1.0f / 255.0f);
    for (int i = tid; i < 2048; i += 320) { int oc = i >> 6, k = i & 63; wt[k * 32 + oc] = w1[i]; }
    if (tid < 32) bs[tid] = b1[tid];
    __syncthreads();

    const int ocg = tid & 7, row = tid >> 3;    // ocg 0..7, row 0..39
    const int oc0 = ocg * 4;
    const int oy = row >> 1, ox0 = (row & 1) * 10;

    float acc[4][10];
    #pragma unroll
    for (int j = 0; j < 4; j++) {
        const float bv = bs[oc0 + j];
        #pragma unroll
        for (int i = 0; i < 10; i++) acc[j][i] = bv;
    }

    for (int ky = 0; ky < 8; ky++) {
        const float* xr = &xs[(oy * 4 + ky) * 84 + ox0 * 4];
        #pragma unroll
        for (int kx = 0; kx < 8; kx++) {
            const float4 w4 = *(const float4*)&wt[(ky * 8 + kx) * 32 + oc0];
            const float wv[4] = {w4.x, w4.y, w4.z, w4.w};
            float xv[10];
            #pragma unroll
            for (int i = 0; i < 10; i++) xv[i] = xr[kx + 4 * i];
            #pragma unroll
            for (int j = 0; j < 4; j++)
                #pragma unroll
                for (int i = 0; i < 10; i++)
                    acc[j][i] += wv[j] * xv[i];
        }
    }

    const size_t base = (size_t)b * 12800 + (size_t)oc0 * 400 + oy * 20 + ox0;
    #pragma unroll
    for (int j = 0; j < 4; j++)
        #pragma unroll
        for (int i = 0; i < 10; i++)
            lif_store_u8(acc[j][i], mem1, s1, base + (size_t)j * 400 + i, t);
}

// ---------------- conv2 + LIF: s1(u8)[b,32,20,20] * w2[64,32,4,4] stride2 -> [b,64,9,9]
// v3: v2's register-reuse (thread = 4 oc x 9 px) + u8-packed LDS input: each
// 20-px row = 5 x b32 LDS reads (vs 5 x b128 of floats) -> LDS pipe no longer
// 5x oversubscribed at the grid-capped 6 waves/CU. cvt of {0,1} exact; FMA
// order per output unchanged -> bit-identical.
__global__ __launch_bounds__(192) void conv2_lif(const unsigned char* __restrict__ s1,
        const float* __restrict__ w2t, const float* __restrict__ b2,
        float* __restrict__ mem2, float* __restrict__ s2, int t)
{
    __shared__ __align__(16) unsigned int insb[3200];  // 12800 u8 = [32 ic][20][20]
    __shared__ __align__(16) float wt[4096];           // [64 k][64 oc] chunk
    __shared__ float bs[64];
    const int b = blockIdx.x, tid = threadIdx.x;
    const uint4* ip = (const uint4*)(s1 + (size_t)b * 12800);
    for (int i = tid; i < 800; i += 192)
        ((uint4*)insb)[i] = ip[i];
    if (tid < 64) bs[tid] = b2[tid];

    const int ocg = tid & 15, row = tid >> 4;   // ocg 0..15, row 0..11 (active < 9)
    const int oc0 = ocg * 4;
    const bool act = (row < 9);

    float acc[4][9];
    bool inited = false;
    for (int kc = 0; kc < 512; kc += 64) {
        __syncthreads();                         // prev compute done (iter0: nothing)
        for (int i = tid; i < 1024; i += 192)
            *(float4*)&wt[i * 4] = *(const float4*)&w2t[(size_t)kc * 64 + i * 4];
        __syncthreads();                         // wt (and, iter 0, insb/bs) visible
        if (!inited) {
            #pragma unroll
            for (int j = 0; j < 4; j++) {
                const float bv = bs[oc0 + j];
                #pragma unroll
                for (int i = 0; i < 9; i++) acc[j][i] = bv;
            }
            inited = true;
        }
        if (act) {
            const int ic0 = kc >> 4;
            #pragma unroll
            for (int icl = 0; icl < 4; icl++) {
                const unsigned char* inc = (const unsigned char*)insb + (ic0 + icl) * 400;
                #pragma unroll
                for (int ky = 0; ky < 4; ky++) {
                    const unsigned int* xr = (const unsigned int*)(inc + (2 * row + ky) * 20);
                    float xv[20];
                    #pragma unroll
                    for (int q = 0; q < 5; q++) {
                        const unsigned int v = xr[q];
                        xv[q * 4 + 0] = (float)(v & 0xffu);
                        xv[q * 4 + 1] = (float)((v >> 8) & 0xffu);
                        xv[q * 4 + 2] = (float)((v >> 16) & 0xffu);
                        xv[q * 4 + 3] = (float)(v >> 24);
                    }
                    #pragma unroll
                    for (int kx = 0; kx < 4; kx++) {
                        const float4 w4 = *(const float4*)&wt[(icl * 16 + ky * 4 + kx) * 64 + oc0];
                        #pragma unroll
                        for (int i = 0; i < 9; i++) {
                            const float xvv = xv[kx + 2 * i];
                            acc[0][i] += w4.x * xvv;
                            acc[1][i] += w4.y * xvv;
                            acc[2][i] += w4.z * xvv;
                            acc[3][i] += w4.w * xvv;
                        }
                    }
                }
            }
        }
    }

    if (act) {
        const size_t base = (size_t)b * 5184 + (size_t)oc0 * 81 + (size_t)row * 9;
        #pragma unroll
        for (int j = 0; j < 4; j++)
            #pragma unroll
            for (int i = 0; i < 9; i++)
                lif_store(acc[j][i], mem2, s2, base + (size_t)j * 81 + i, t);
    }
}

// ---------------- conv3 + LIF: s2[b,64,9,9] * w3[64,64,3,3] stride1 -> [b,64,7,7]
__global__ __launch_bounds__(256) void conv3_lif(const float* __restrict__ s2,
        const float* __restrict__ w3t, const float* __restrict__ b3,
        float* __restrict__ mem3, float* __restrict__ s3, int t)
{
    __shared__ float ins[5184];
    __shared__ __align__(8) float wt[72 * 64];  // [kl][oc], K-chunk 72 = 8 ic x 9
    __shared__ float bs[64];
    const int b = blockIdx.x, tid = threadIdx.x;
    const float* ip = s2 + (size_t)b * 5184;
    for (int i = tid; i < 5184; i += 256) ins[i] = ip[i];
    if (tid < 64) bs[tid] = b3[tid];

    const int ocg = tid & 31, oy = tid >> 5;    // oy 0..7
    const int oc0 = ocg * 2;
    const bool act = (oy < 7);
    __syncthreads();

    float acc[2][7];
    #pragma unroll
    for (int j = 0; j < 2; j++) {
        const float bv = bs[oc0 + j];
        #pragma unroll
        for (int i = 0; i < 7; i++) acc[j][i] = bv;
    }

    for (int kc = 0; kc < 576; kc += 72) {
        for (int i = tid; i < 4608; i += 256) wt[i] = w3t[kc * 64 + i];
        __syncthreads();
        if (act) {
            const int ic0 = kc / 9;
            #pragma unroll
            for (int icl = 0; icl < 8; icl++) {
                const float* inc = &ins[(ic0 + icl) * 81];
                #pragma unroll
                for (int ky = 0; ky < 3; ky++) {
                    const float* xr = &inc[(oy + ky) * 9];
                    float xv[9];
                    #pragma unroll
                    for (int i = 0; i < 9; i++) xv[i] = xr[i];
                    #pragma unroll
                    for (int kx = 0; kx < 3; kx++) {
                        const float2 w2v = *(const float2*)&wt[(icl * 9 + ky * 3 + kx) * 64 + oc0];
                        #pragma unroll
                        for (int i = 0; i < 7; i++) {
                            acc[0][i] += w2v.x * xv[kx + i];
                            acc[1][i] += w2v.y * xv[kx + i];
                        }
                    }
                }
            }
        }
        __syncthreads();
    }

    if (act) {
        const size_t base = (size_t)b * 3136 + (size_t)oc0 * 49 + oy * 7;
        #pragma unroll
        for (int j = 0; j < 2; j++)
            #pragma unroll
            for (int i = 0; i < 7; i++)
                lif_store(acc[j][i], mem3, s3, base + (size_t)j * 49 + i, t);
    }
}

// ---------------- transpose [512][3136] -> [3136][512], z=0: s3->s3t, z=1: wl->wlt
__global__ __launch_bounds__(256) void transpose_mk(const float* __restrict__ s3,
        const float* __restrict__ wl, float* __restrict__ s3t, float* __restrict__ wlt)
{
    __shared__ float T[64][65];
    const int c0 = blockIdx.x * 64;               // 49 tiles along K=3136
    const int r0 = blockIdx.y * 64;               // 8 tiles along M=512
    const float* src = blockIdx.z ? wl : s3;
    float* dst = blockIdx.z ? wlt : s3t;
    const int tid = threadIdx.x;
    #pragma unroll
    for (int i = 0; i < 4; i++) {
        const int f = tid + 256 * i;              // 0..1023
        const int r = f >> 4, cq = (f & 15) * 4;
        const float4 v = *(const float4*)&src[(size_t)(r0 + r) * 3136 + c0 + cq];
        T[r][cq + 0] = v.x; T[r][cq + 1] = v.y; T[r][cq + 2] = v.z; T[r][cq + 3] = v.w;
    }
    __syncthreads();
    #pragma unroll
    for (int i = 0; i < 4; i++) {
        const int f = tid + 256 * i;
        const int c = f >> 4, rq = (f & 15) * 4;
        float4 v;
        v.x = T[rq + 0][c]; v.y = T[rq + 1][c]; v.z = T[rq + 2][c]; v.w = T[rq + 3][c];
        *(float4*)&dst[(size_t)(c0 + c) * 512 + r0 + rq] = v;
    }
}

// ---------------- fc partial GEMM: out[m][n] = sum_k s3t[k][m]*wlt[k][n]
// 64x64 tile, 4x4/thread, SPLITK=7 (448 k each = 7 chunks of 64, sequential -> deterministic)
__global__ __launch_bounds__(256) void fc_gemm(const float* __restrict__ s3t,
        const float* __restrict__ wlt, float* __restrict__ part)
{
    __shared__ __align__(16) float As[64][68];
    __shared__ __align__(16) float Bs[64][68];
    const int bid = blockIdx.x;                   // 448 = 64 tiles x 7 splits
    const int tile = bid & 63, split = bid >> 6;
    const int m0 = (tile & 7) * 64, n0 = (tile >> 3) * 64;
    const int tid = threadIdx.x;
    const int tn = (tid & 15) * 4, tm = (tid >> 4) * 4;
    float acc[4][4] = {};

    for (int sc = 0; sc < 7; sc++) {
        const int kc = split * 448 + sc * 64;
        __syncthreads();
        #pragma unroll
        for (int i = 0; i < 4; i++) {
            const int f = tid + 256 * i;          // 0..1023
            const int k = f >> 4, mq = (f & 15) * 4;
            *(float4*)&As[k][mq] = *(const float4*)&s3t[(size_t)(kc + k) * 512 + m0 + mq];
            *(float4*)&Bs[k][mq] = *(const float4*)&wlt[(size_t)(kc + k) * 512 + n0 + mq];
        }
        __syncthreads();
        #pragma unroll 8
        for (int k = 0; k < 64; k++) {
            const float4 a = *(const float4*)&As[k][tm];
            const float4 b = *(const float4*)&Bs[k][tn];
            acc[0][0] += a.x * b.x; acc[0][1] += a.x * b.y; acc[0][2] += a.x * b.z; acc[0][3] += a.x * b.w;
            acc[1][0] += a.y * b.x; acc[1][1] += a.y * b.y; acc[1][2] += a.y * b.z; acc[1][3] += a.y * b.w;
            acc[2][0] += a.z * b.x; acc[2][1] += a.z * b.y; acc[2][2] += a.z * b.z; acc[2][3] += a.z * b.w;
            acc[3][0] += a.w * b.x; acc[3][1] += a.w * b.y; acc[3][2] += a.w * b.z; acc[3][3] += a.w * b.w;
        }
    }

    #pragma unroll
    for (int r = 0; r < 4; r++) {
        float4 v; v.x = acc[r][0]; v.y = acc[r][1]; v.z = acc[r][2]; v.w = acc[r][3];
        *(float4*)&part[(size_t)split * 262144 + (size_t)(m0 + tm + r) * 512 + n0 + tn] = v;
    }
}

// ---------------- fc reduce (fixed order) + bias + LIF + spike accumulate
__global__ __launch_bounds__(256) void fc_reduce_lif(const float* __restrict__ part,
        const float* __restrict__ bl, float* __restrict__ memf,
        float* __restrict__ accum, int t)
{
    const int gid = blockIdx.x * 256 + threadIdx.x;  // grid 1024 -> 262144 exact
    const int n = gid & 511;
    float s = part[gid];
    #pragma unroll
    for (int sp = 1; sp < 7; sp++) s += part[(size_t)sp * 262144 + gid];
    s += bl[n];
    const float mp = t ? memf[gid] : 0.0f;
    const float r = (mp > 1.0f) ? 1.0f : 0.0f;
    const float mnew = BETA * mp + s - r;
    memf[gid] = mnew;
    const float spk = (mnew > 1.0f) ? 1.0f : 0.0f;
    accum[gid] = (t ? accum[gid] : 0.0f) + spk;
}

// ---------------- head: out[512,18] = (acc/4) @ wh.T + bh
__global__ void head_k(const float* __restrict__ accum, const float* __restrict__ wh,
                       const float* __restrict__ bh, float* __restrict__ out)
{
    const int gid = blockIdx.x * 256 + threadIdx.x;
    if (gid >= 512 * 18) return;
    const int b = gid / 18, o = gid - b * 18;
    const float* av = accum + (size_t)b * 512;
    const float* wv = wh + (size_t)o * 512;
    float s = bh[o];
    for (int k = 0; k < 512; k++) s += (av[k] * 0.25f) * wv[k];
    out[gid] = s;
}

extern "C" void kernel_launch(void* const* d_in, const int* in_sizes, int n_in,
                              void* d_out, int out_size, void* d_ws, size_t ws_size,
                              hipStream_t stream)
{
    const float* x  = (const float*)d_in[0];
    const float* w1 = (const float*)d_in[1];
    const float* b1 = (const float*)d_in[2];
    const float* w2 = (const float*)d_in[3];
    const float* b2 = (const float*)d_in[4];
    const float* w3 = (const float*)d_in[5];
    const float* b3 = (const float*)d_in[6];
    const float* wl = (const float*)d_in[7];
    const float* bl = (const float*)d_in[8];
    const float* wh = (const float*)d_in[9];
    const float* bh = (const float*)d_in[10];

    float* ws   = (float*)d_ws;
    float* mem1 = ws;                    // [512][32][400]
    float* mem2 = mem1 + 6553600;        // [512][64][81]
    float* mem3 = mem2 + 2654208;        // [512][64][49]
    float* memf = mem3 + 1605632;        // [512][512]
    float* acc  = memf + 262144;         // [512][512]
    float* s1   = acc  + 262144;         // region: 6,553,600 floats
    float* s2   = s1 + 6553600;          // [512][64][81]
    float* s3   = s2 + 2654208;          // [512][64][49]
    float* w2t  = s3 + 1605632;          // [512][64]
    float* w3t  = w2t + 32768;           // [576][64]

    // s1 spikes now u8 (6,553,600 BYTES at the start of the s1 region).
    unsigned char* s1u8 = (unsigned char*)s1;

    // fc scratch ALIASES the s1 region: s1u8 is dead after conv2(t) and rewritten
    // by conv1(t+1); fc scratch is produced after conv3(t) and consumed by
    // fc_reduce(t) -> no overlap with s1u8's live range (sequential stream).
    float* s3t_buf = s1;                 // [3136][512]  (1,605,632 floats)
    float* wlt_buf = s1 + 1605632;       // [3136][512]  (1,605,632 floats)
    float* part    = s1 + 3211264;       // [7][512][512] (1,835,008 floats) -> total 5,046,272 < 6,553,600

    transpose_w23<<<144, 256, 0, stream>>>(w2, w3, w2t, w3t);

    for (int t = 0; t < 4; t++) {
        conv1_lif<<<512, 320, 0, stream>>>(x, w1, b1, mem1, s1u8, t);
        conv2_lif<<<512, 192, 0, stream>>>(s1u8, w2t, b2, mem2, s2, t);
        conv3_lif<<<512, 256, 0, stream>>>(s2, w3t, b3, mem3, s3, t);
        transpose_mk<<<dim3(49, 8, 2), 256, 0, stream>>>(s3, wl, s3t_buf, wlt_buf);
        fc_gemm<<<448, 256, 0, stream>>>(s3t_buf, wlt_buf, part);
        fc_reduce_lif<<<1024, 256, 0, stream>>>(part, bl, memf, acc, t);
    }
    head_k<<<36, 256, 0, stream>>>(acc, wh, bh, (float*)d_out);
}